// Round 1
// baseline (12727.147 us; speedup 1.0000x reference)
//
#include <hip/hip_runtime.h>
#include <hip/hip_bf16.h>

// GNN_node: HammerGNN-style bipartite GCN on MI355X.
// Round 1: correctness-first. fp32 tiled GEMM + atomic edge scatter.
// ws layout: A (x buffer) | B (agg/h buffer) | h0 | deg1 | dinv1 | deg2 | dinv2

#define N_INST 300000
#define N_NET  100000
#define N_TOT  400000
#define EMB    128

#define LEAKY(v) ((v) > 0.f ? (v) : 0.1f * (v))

static constexpr size_t NF = (size_t)N_TOT * EMB;  // floats per node-feature buffer

// ---------------- generic tiled GEMM: C[M,N] = act(A[M,K] @ W[N,K]^T + b) -------------
__global__ __launch_bounds__(256) void gemm_bias_act(
    const float* __restrict__ A, const float* __restrict__ W,
    const float* __restrict__ bias, float* __restrict__ C,
    int M, int N, int K, int act)
{
    __shared__ float As[16][64];
    __shared__ float Bs[16][64];
    const int t  = threadIdx.x;
    const int tx = t & 15, ty = t >> 4;
    const int m0 = blockIdx.y << 6, n0 = blockIdx.x << 6;
    const int r  = t >> 2, kg = (t & 3) << 2;   // loader coords: row 0..63, k-group
    float acc[4][4] = {};

    for (int k0 = 0; k0 < K; k0 += 16) {
        float4 va = make_float4(0.f, 0.f, 0.f, 0.f);
        float4 vb = make_float4(0.f, 0.f, 0.f, 0.f);
        if (m0 + r < M) va = *(const float4*)&A[(size_t)(m0 + r) * K + (k0 + kg)];
        if (n0 + r < N) vb = *(const float4*)&W[(size_t)(n0 + r) * K + (k0 + kg)];
        __syncthreads();
        As[kg + 0][r] = va.x; As[kg + 1][r] = va.y; As[kg + 2][r] = va.z; As[kg + 3][r] = va.w;
        Bs[kg + 0][r] = vb.x; Bs[kg + 1][r] = vb.y; Bs[kg + 2][r] = vb.z; Bs[kg + 3][r] = vb.w;
        __syncthreads();
        #pragma unroll
        for (int k = 0; k < 16; ++k) {
            float4 a4 = *(const float4*)&As[k][ty << 2];
            float4 b4 = *(const float4*)&Bs[k][tx << 2];
            float av[4] = {a4.x, a4.y, a4.z, a4.w};
            float bv[4] = {b4.x, b4.y, b4.z, b4.w};
            #pragma unroll
            for (int i = 0; i < 4; ++i)
                #pragma unroll
                for (int j = 0; j < 4; ++j)
                    acc[i][j] = fmaf(av[i], bv[j], acc[i][j]);
        }
    }
    #pragma unroll
    for (int i = 0; i < 4; ++i) {
        int m = m0 + (ty << 2) + i;
        if (m >= M) continue;
        #pragma unroll
        for (int j = 0; j < 4; ++j) {
            int n = n0 + (tx << 2) + j;
            if (n >= N) continue;
            float v = acc[i][j] + bias[n];
            if (act) v = LEAKY(v);
            C[(size_t)m * N + n] = v;
        }
    }
}

// ---------------- degree helpers ----------------
__global__ __launch_bounds__(256) void zero_f32(float* __restrict__ p, int n) {
    int i = blockIdx.x * 256 + threadIdx.x;
    if (i < n) p[i] = 0.f;
}

__global__ __launch_bounds__(256) void count_deg(const int* __restrict__ row,
                                                 float* __restrict__ deg, int E) {
    int e = blockIdx.x * 256 + threadIdx.x;
    if (e < E) unsafeAtomicAdd(&deg[row[e]], 1.0f);
}

__global__ __launch_bounds__(256) void finish_deg(float* __restrict__ deg,
                                                  float* __restrict__ dinv, int n) {
    int i = blockIdx.x * 256 + threadIdx.x;
    if (i < n) {
        float d = deg[i] + 1.0f;   // reference: segment_sum(ones) + 1
        deg[i]  = d;
        dinv[i] = rsqrtf(d);
    }
}

// ---------------- conv pieces ----------------
// outb[i][f] = relu(x[i][f] + root[f]) / deg[i]   (the "self/root" term; scatter adds on top)
__global__ __launch_bounds__(256) void init_out(const float* __restrict__ x,
                                                const float* __restrict__ root,
                                                const float* __restrict__ deg,
                                                float* __restrict__ outb) {
    int idx = blockIdx.x * 256 + threadIdx.x;
    if (idx >= N_TOT * 32) return;
    int i = idx >> 5, g = (idx & 31) << 2;
    float invd = 1.0f / deg[i];
    float4 v = *(const float4*)&x[(size_t)i * EMB + g];
    float4 o;
    o.x = fmaxf(v.x + root[g + 0], 0.f) * invd;
    o.y = fmaxf(v.y + root[g + 1], 0.f) * invd;
    o.z = fmaxf(v.z + root[g + 2], 0.f) * invd;
    o.w = fmaxf(v.w + root[g + 3], 0.f) * invd;
    *(float4*)&outb[(size_t)i * EMB + g] = o;
}

// out[col[e]] += dinv[row]*dinv[col] * relu(x[row[e]])   — one wave per edge
__global__ __launch_bounds__(256) void scatter_edges(const float* __restrict__ x,
                                                     const int* __restrict__ row,
                                                     const int* __restrict__ col,
                                                     const float* __restrict__ dinv,
                                                     float* __restrict__ outb, int E) {
    int e = blockIdx.x * 4 + (threadIdx.x >> 6);
    if (e >= E) return;
    int lane = threadIdx.x & 63;
    int r = row[e], c = col[e];
    float w = dinv[r] * dinv[c];
    float2 v = *(const float2*)&x[(size_t)r * EMB + lane * 2];
    float mx = fmaxf(v.x, 0.f) * w;
    float my = fmaxf(v.y, 0.f) * w;
    float* o = &outb[(size_t)c * EMB + lane * 2];
    unsafeAtomicAdd(o, mx);
    unsafeAtomicAdd(o + 1, my);
}

// h = leaky(LN(h + h0)); also write net-node rows to out[:, slice*128:...]
__global__ __launch_bounds__(256) void ln_final(float* __restrict__ h,
                                                const float* __restrict__ h0,
                                                const float* __restrict__ gw,
                                                const float* __restrict__ bw,
                                                float* __restrict__ out, int slice) {
    int i = blockIdx.x * 4 + (threadIdx.x >> 6);
    if (i >= N_TOT) return;
    int lane = threadIdx.x & 63;
    size_t base = (size_t)i * EMB + lane * 2;
    float2 t2 = *(const float2*)&h[base];
    float2 z2 = *(const float2*)&h0[base];
    float t0 = t2.x + z2.x, t1 = t2.y + z2.y;
    float s = t0 + t1, sq = t0 * t0 + t1 * t1;
    #pragma unroll
    for (int o = 1; o < 64; o <<= 1) {
        s  += __shfl_xor(s, o);
        sq += __shfl_xor(sq, o);
    }
    float m   = s * (1.f / 128.f);
    float var = sq * (1.f / 128.f) - m * m;
    float rs  = rsqrtf(var + 1e-5f);
    int f = lane * 2;
    float y0 = (t0 - m) * rs * gw[f]     + bw[f];
    float y1 = (t1 - m) * rs * gw[f + 1] + bw[f + 1];
    y0 = LEAKY(y0); y1 = LEAKY(y1);
    *(float2*)&h[base] = make_float2(y0, y1);
    if (i >= N_INST) {
        size_t ob = (size_t)(i - N_INST) * 512 + (size_t)slice * EMB + f;
        *(float2*)&out[ob] = make_float2(y0, y1);
    }
}

// out[:, 0:128] = h0 net rows
__global__ __launch_bounds__(256) void copy_h0_out(const float* __restrict__ h0,
                                                   float* __restrict__ out) {
    int idx = blockIdx.x * 256 + threadIdx.x;
    if (idx >= N_NET * 32) return;
    int n = idx >> 5, g = (idx & 31) << 2;
    float4 v = *(const float4*)&h0[(size_t)(N_INST + n) * EMB + g];
    *(float4*)&out[(size_t)n * 512 + g] = v;
}

// ---------------- host side ----------------
extern "C" void kernel_launch(void* const* d_in, const int* in_sizes, int n_in,
                              void* d_out, int out_size, void* d_ws, size_t ws_size,
                              hipStream_t stream)
{
    const float* x        = (const float*)d_in[0];
    const float* x_net    = (const float*)d_in[1];
    const int*   ei1      = (const int*)d_in[2];
    const int*   ei2      = (const int*)d_in[3];
    const float* enc1_W   = (const float*)d_in[5];
    const float* enc1_b   = (const float*)d_in[6];
    const float* enc2_W   = (const float*)d_in[7];
    const float* enc2_b   = (const float*)d_in[8];
    const float* encn1_W  = (const float*)d_in[9];
    const float* encn1_b  = (const float*)d_in[10];
    const float* encn2_W  = (const float*)d_in[11];
    const float* encn2_b  = (const float*)d_in[12];
    const float* conv_W   = (const float*)d_in[13];
    const float* conv_b   = (const float*)d_in[14];
    const float* conv_root= (const float*)d_in[15];
    const float* reconv_W = (const float*)d_in[16];
    const float* reconv_b = (const float*)d_in[17];
    const float* reconv_root = (const float*)d_in[18];
    const float* ln_g     = (const float*)d_in[19];
    const float* ln_b     = (const float*)d_in[20];
    float* out = (float*)d_out;

    const int E1 = in_sizes[2] / 2;
    const int E2 = in_sizes[3] / 2;
    const int* row1 = ei1;       const int* col1 = ei1 + E1;
    const int* row2 = ei2;       const int* col2 = ei2 + E2;

    float* A     = (float*)d_ws;        // x-buffer (also encoder hidden scratch)
    float* B     = A  + NF;             // agg / h buffer
    float* h0    = B  + NF;
    float* deg1  = h0 + NF;
    float* dinv1 = deg1 + N_TOT;
    float* deg2  = dinv1 + N_TOT;
    float* dinv2 = deg2 + N_TOT;

    // ---- encoders (hidden buffers live in A..B scratch) ----
    float* hid = A;  // [300000, 256] spans A and part of B
    gemm_bias_act<<<dim3(4, (N_INST + 63) / 64), 256, 0, stream>>>(
        x, enc1_W, enc1_b, hid, N_INST, 256, 64, 1);
    gemm_bias_act<<<dim3(2, (N_INST + 63) / 64), 256, 0, stream>>>(
        hid, enc2_W, enc2_b, h0, N_INST, 128, 256, 1);
    float* hidn = A;  // [100000, 128]
    gemm_bias_act<<<dim3(2, (N_NET + 63) / 64), 256, 0, stream>>>(
        x_net, encn1_W, encn1_b, hidn, N_NET, 128, 64, 1);
    gemm_bias_act<<<dim3(2, (N_NET + 63) / 64), 256, 0, stream>>>(
        hidn, encn2_W, encn2_b, h0 + (size_t)N_INST * EMB, N_NET, 128, 128, 1);
    copy_h0_out<<<(N_NET * 32 + 255) / 256, 256, 0, stream>>>(h0, out);

    // ---- degrees (once per launch; edge sets are fixed across layers) ----
    zero_f32<<<(N_TOT + 255) / 256, 256, 0, stream>>>(deg1, N_TOT);
    zero_f32<<<(N_TOT + 255) / 256, 256, 0, stream>>>(deg2, N_TOT);
    count_deg<<<(E1 + 255) / 256, 256, 0, stream>>>(row1, deg1, E1);
    count_deg<<<(E2 + 255) / 256, 256, 0, stream>>>(row2, deg2, E2);
    finish_deg<<<(N_TOT + 255) / 256, 256, 0, stream>>>(deg1, dinv1, N_TOT);
    finish_deg<<<(N_TOT + 255) / 256, 256, 0, stream>>>(deg2, dinv2, N_TOT);

    // ---- 3 layers x (conv, re_conv) ----
    const float* hcur = h0;
    for (int l = 0; l < 3; ++l) {
        gemm_bias_act<<<dim3(2, (N_TOT + 63) / 64), 256, 0, stream>>>(
            hcur, conv_W + (size_t)l * EMB * EMB, conv_b + l * EMB, A, N_TOT, EMB, EMB, 0);
        init_out<<<(N_TOT * 32 + 255) / 256, 256, 0, stream>>>(A, conv_root + l * EMB, deg1, B);
        scatter_edges<<<(E1 + 3) / 4, 256, 0, stream>>>(A, row1, col1, dinv1, B, E1);

        gemm_bias_act<<<dim3(2, (N_TOT + 63) / 64), 256, 0, stream>>>(
            B, reconv_W + (size_t)l * EMB * EMB, reconv_b + l * EMB, A, N_TOT, EMB, EMB, 0);
        init_out<<<(N_TOT * 32 + 255) / 256, 256, 0, stream>>>(A, reconv_root + l * EMB, deg2, B);
        scatter_edges<<<(E2 + 3) / 4, 256, 0, stream>>>(A, row2, col2, dinv2, B, E2);

        ln_final<<<(N_TOT + 3) / 4, 256, 0, stream>>>(B, h0, ln_g + l * EMB, ln_b + l * EMB, out, l + 1);
        hcur = B;
    }
}

// Round 2
// 4972.591 us; speedup vs baseline: 2.5595x; 2.5595x over previous
//
#include <hip/hip_runtime.h>
#include <hip/hip_bf16.h>

// GNN_node: bipartite GCN on MI355X.
// Round 2: CSR gather replaces atomic scatter (scatter was 9.8ms of 12.7ms).
// ws layout: A | B | h0 | deg1 dinv1 deg2 dinv2 | off1 src1 off2 src2 | cnt | bsum

#define N_INST 300000
#define N_NET  100000
#define N_TOT  400000
#define EMB    128
#define NB_SCAN ((N_TOT + 1023) / 1024)   // blocks for 1024-wide scan = 391

#define LEAKY(v) ((v) > 0.f ? (v) : 0.1f * (v))

static constexpr size_t NF = (size_t)N_TOT * EMB;

// ---------------- generic tiled GEMM: C[M,N] = act(A[M,K] @ W[N,K]^T + b) -------------
__global__ __launch_bounds__(256) void gemm_bias_act(
    const float* __restrict__ A, const float* __restrict__ W,
    const float* __restrict__ bias, float* __restrict__ C,
    int M, int N, int K, int act)
{
    __shared__ float As[16][64];
    __shared__ float Bs[16][64];
    const int t  = threadIdx.x;
    const int tx = t & 15, ty = t >> 4;
    const int m0 = blockIdx.y << 6, n0 = blockIdx.x << 6;
    const int r  = t >> 2, kg = (t & 3) << 2;
    float acc[4][4] = {};

    for (int k0 = 0; k0 < K; k0 += 16) {
        float4 va = make_float4(0.f, 0.f, 0.f, 0.f);
        float4 vb = make_float4(0.f, 0.f, 0.f, 0.f);
        if (m0 + r < M) va = *(const float4*)&A[(size_t)(m0 + r) * K + (k0 + kg)];
        if (n0 + r < N) vb = *(const float4*)&W[(size_t)(n0 + r) * K + (k0 + kg)];
        __syncthreads();
        As[kg + 0][r] = va.x; As[kg + 1][r] = va.y; As[kg + 2][r] = va.z; As[kg + 3][r] = va.w;
        Bs[kg + 0][r] = vb.x; Bs[kg + 1][r] = vb.y; Bs[kg + 2][r] = vb.z; Bs[kg + 3][r] = vb.w;
        __syncthreads();
        #pragma unroll
        for (int k = 0; k < 16; ++k) {
            float4 a4 = *(const float4*)&As[k][ty << 2];
            float4 b4 = *(const float4*)&Bs[k][tx << 2];
            float av[4] = {a4.x, a4.y, a4.z, a4.w};
            float bv[4] = {b4.x, b4.y, b4.z, b4.w};
            #pragma unroll
            for (int i = 0; i < 4; ++i)
                #pragma unroll
                for (int j = 0; j < 4; ++j)
                    acc[i][j] = fmaf(av[i], bv[j], acc[i][j]);
        }
    }
    #pragma unroll
    for (int i = 0; i < 4; ++i) {
        int m = m0 + (ty << 2) + i;
        if (m >= M) continue;
        #pragma unroll
        for (int j = 0; j < 4; ++j) {
            int n = n0 + (tx << 2) + j;
            if (n >= N) continue;
            float v = acc[i][j] + bias[n];
            if (act) v = LEAKY(v);
            C[(size_t)m * N + n] = v;
        }
    }
}

// ---------------- small utility kernels ----------------
__global__ __launch_bounds__(256) void zero_i32(int* __restrict__ p, int n) {
    int i = blockIdx.x * 256 + threadIdx.x;
    if (i < n) p[i] = 0;
}

__global__ __launch_bounds__(256) void count_idx(const int* __restrict__ idx,
                                                 int* __restrict__ cnt, int E) {
    int e = blockIdx.x * 256 + threadIdx.x;
    if (e < E) atomicAdd(&cnt[idx[e]], 1);
}

__global__ __launch_bounds__(256) void finish_deg(const int* __restrict__ rowcnt,
                                                  float* __restrict__ deg,
                                                  float* __restrict__ dinv, int n) {
    int i = blockIdx.x * 256 + threadIdx.x;
    if (i < n) {
        float d = (float)rowcnt[i] + 1.0f;
        deg[i]  = d;
        dinv[i] = rsqrtf(d);
    }
}

// ---------------- scan (1024 elems / block) ----------------
__global__ __launch_bounds__(256) void scan_block(const int* __restrict__ cnt,
                                                  int* __restrict__ off,
                                                  int* __restrict__ bsum, int n) {
    __shared__ int sh[256];
    int t = threadIdx.x;
    int base = blockIdx.x * 1024 + t * 4;
    int v0 = base + 0 < n ? cnt[base + 0] : 0;
    int v1 = base + 1 < n ? cnt[base + 1] : 0;
    int v2 = base + 2 < n ? cnt[base + 2] : 0;
    int v3 = base + 3 < n ? cnt[base + 3] : 0;
    int s01 = v0 + v1, loc = s01 + v2 + v3;
    sh[t] = loc;
    __syncthreads();
    #pragma unroll
    for (int o = 1; o < 256; o <<= 1) {
        int x_ = (t >= o) ? sh[t - o] : 0;
        __syncthreads();
        sh[t] += x_;
        __syncthreads();
    }
    int excl = sh[t] - loc;
    if (t == 255) bsum[blockIdx.x] = sh[255];
    if (base + 0 < n) off[base + 0] = excl;
    if (base + 1 < n) off[base + 1] = excl + v0;
    if (base + 2 < n) off[base + 2] = excl + s01;
    if (base + 3 < n) off[base + 3] = excl + s01 + v2;
}

__global__ __launch_bounds__(512) void scan_small(int* __restrict__ bsum, int nb,
                                                  int* __restrict__ off_end) {
    __shared__ int sh[512];
    int t = threadIdx.x;
    int v = t < nb ? bsum[t] : 0;
    sh[t] = v;
    __syncthreads();
    #pragma unroll
    for (int o = 1; o < 512; o <<= 1) {
        int x_ = (t >= o) ? sh[t - o] : 0;
        __syncthreads();
        sh[t] += x_;
        __syncthreads();
    }
    if (t < nb) bsum[t] = sh[t] - v;
    if (t == 511) *off_end = sh[511];
}

__global__ __launch_bounds__(256) void add_boff(int* __restrict__ off,
                                                const int* __restrict__ bsum, int n) {
    int i = blockIdx.x * 256 + threadIdx.x;
    if (i < n) off[i] += bsum[i >> 10];
}

__global__ __launch_bounds__(256) void fill_csr(const int* __restrict__ row,
                                                const int* __restrict__ col,
                                                int* __restrict__ cursor,
                                                const int* __restrict__ off,
                                                int* __restrict__ src, int E) {
    int e = blockIdx.x * 256 + threadIdx.x;
    if (e >= E) return;
    int c = col[e];
    int p = off[c] + atomicAdd(&cursor[c], 1);
    src[p] = row[e];
}

// ---------------- fused conv aggregate (CSR gather + self/root term) ----------------
// outb[i] = relu(x[i]+root)/deg[i] + sum_{e in CSR(i)} dinv[src]*dinv[i]*relu(x[src])
__global__ __launch_bounds__(256) void gather_conv(const float* __restrict__ x,
                                                   const int* __restrict__ off,
                                                   const int* __restrict__ src,
                                                   const float* __restrict__ dinv,
                                                   const float* __restrict__ deg,
                                                   const float* __restrict__ root,
                                                   float* __restrict__ outb) {
    int i = blockIdx.x * 4 + (threadIdx.x >> 6);
    if (i >= N_TOT) return;
    int lane = threadIdx.x & 63;
    int f = lane * 2;
    float2 xv = *(const float2*)&x[(size_t)i * EMB + f];
    float invd = 1.0f / deg[i];
    float r0 = root[f], r1 = root[f + 1];
    float a0 = fmaxf(xv.x + r0, 0.f) * invd;
    float a1 = fmaxf(xv.y + r1, 0.f) * invd;
    float di = dinv[i];
    int e0 = off[i], e1 = off[i + 1];
    for (int e = e0; e < e1; ++e) {
        int s = src[e];
        float w = dinv[s] * di;
        float2 v = *(const float2*)&x[(size_t)s * EMB + f];
        a0 = fmaf(fmaxf(v.x, 0.f), w, a0);
        a1 = fmaf(fmaxf(v.y, 0.f), w, a1);
    }
    *(float2*)&outb[(size_t)i * EMB + f] = make_float2(a0, a1);
}

// ---------------- layernorm + residual + leaky + JK-output ----------------
__global__ __launch_bounds__(256) void ln_final(float* __restrict__ h,
                                                const float* __restrict__ h0,
                                                const float* __restrict__ gw,
                                                const float* __restrict__ bw,
                                                float* __restrict__ out, int slice) {
    int i = blockIdx.x * 4 + (threadIdx.x >> 6);
    if (i >= N_TOT) return;
    int lane = threadIdx.x & 63;
    size_t base = (size_t)i * EMB + lane * 2;
    float2 t2 = *(const float2*)&h[base];
    float2 z2 = *(const float2*)&h0[base];
    float t0 = t2.x + z2.x, t1 = t2.y + z2.y;
    float s = t0 + t1, sq = t0 * t0 + t1 * t1;
    #pragma unroll
    for (int o = 1; o < 64; o <<= 1) {
        s  += __shfl_xor(s, o);
        sq += __shfl_xor(sq, o);
    }
    float m   = s * (1.f / 128.f);
    float var = sq * (1.f / 128.f) - m * m;
    float rs  = rsqrtf(var + 1e-5f);
    int f = lane * 2;
    float y0 = (t0 - m) * rs * gw[f]     + bw[f];
    float y1 = (t1 - m) * rs * gw[f + 1] + bw[f + 1];
    y0 = LEAKY(y0); y1 = LEAKY(y1);
    *(float2*)&h[base] = make_float2(y0, y1);
    if (i >= N_INST) {
        size_t ob = (size_t)(i - N_INST) * 512 + (size_t)slice * EMB + f;
        *(float2*)&out[ob] = make_float2(y0, y1);
    }
}

__global__ __launch_bounds__(256) void copy_h0_out(const float* __restrict__ h0,
                                                   float* __restrict__ out) {
    int idx = blockIdx.x * 256 + threadIdx.x;
    if (idx >= N_NET * 32) return;
    int n = idx >> 5, g = (idx & 31) << 2;
    float4 v = *(const float4*)&h0[(size_t)(N_INST + n) * EMB + g];
    *(float4*)&out[(size_t)n * 512 + g] = v;
}

// ---------------- host side ----------------
extern "C" void kernel_launch(void* const* d_in, const int* in_sizes, int n_in,
                              void* d_out, int out_size, void* d_ws, size_t ws_size,
                              hipStream_t stream)
{
    const float* x        = (const float*)d_in[0];
    const float* x_net    = (const float*)d_in[1];
    const int*   ei1      = (const int*)d_in[2];
    const int*   ei2      = (const int*)d_in[3];
    const float* enc1_W   = (const float*)d_in[5];
    const float* enc1_b   = (const float*)d_in[6];
    const float* enc2_W   = (const float*)d_in[7];
    const float* enc2_b   = (const float*)d_in[8];
    const float* encn1_W  = (const float*)d_in[9];
    const float* encn1_b  = (const float*)d_in[10];
    const float* encn2_W  = (const float*)d_in[11];
    const float* encn2_b  = (const float*)d_in[12];
    const float* conv_W   = (const float*)d_in[13];
    const float* conv_b   = (const float*)d_in[14];
    const float* conv_root= (const float*)d_in[15];
    const float* reconv_W = (const float*)d_in[16];
    const float* reconv_b = (const float*)d_in[17];
    const float* reconv_root = (const float*)d_in[18];
    const float* ln_g     = (const float*)d_in[19];
    const float* ln_b     = (const float*)d_in[20];
    float* out = (float*)d_out;

    const int E1 = in_sizes[2] / 2;
    const int E2 = in_sizes[3] / 2;
    const int* row1 = ei1;       const int* col1 = ei1 + E1;
    const int* row2 = ei2;       const int* col2 = ei2 + E2;

    float* A     = (float*)d_ws;
    float* B     = A  + NF;
    float* h0    = B  + NF;
    float* deg1  = h0 + NF;
    float* dinv1 = deg1 + N_TOT;
    float* deg2  = dinv1 + N_TOT;
    float* dinv2 = deg2 + N_TOT;
    int*   off1  = (int*)(dinv2 + N_TOT);      // N_TOT+1
    int*   src1  = off1 + (N_TOT + 1);         // E1
    int*   off2  = src1 + E1;                  // N_TOT+1
    int*   src2  = off2 + (N_TOT + 1);         // E2
    int*   cnt   = src2 + E2;                  // N_TOT (count / cursor scratch)
    int*   bsum  = cnt + N_TOT;                // NB_SCAN

    // ---- encoders ----
    float* hid = A;  // [300000, 256] spans A and part of B
    gemm_bias_act<<<dim3(4, (N_INST + 63) / 64), 256, 0, stream>>>(
        x, enc1_W, enc1_b, hid, N_INST, 256, 64, 1);
    gemm_bias_act<<<dim3(2, (N_INST + 63) / 64), 256, 0, stream>>>(
        hid, enc2_W, enc2_b, h0, N_INST, 128, 256, 1);
    float* hidn = A;
    gemm_bias_act<<<dim3(2, (N_NET + 63) / 64), 256, 0, stream>>>(
        x_net, encn1_W, encn1_b, hidn, N_NET, 128, 64, 1);
    gemm_bias_act<<<dim3(2, (N_NET + 63) / 64), 256, 0, stream>>>(
        hidn, encn2_W, encn2_b, h0 + (size_t)N_INST * EMB, N_NET, 128, 128, 1);
    copy_h0_out<<<(N_NET * 32 + 255) / 256, 256, 0, stream>>>(h0, out);

    const int gE1 = (E1 + 255) / 256, gE2 = (E2 + 255) / 256;
    const int gN  = (N_TOT + 255) / 256;

    // ---- degrees (row counts) + CSR build (col-sorted), per edge set ----
    // set 1
    zero_i32<<<gN, 256, 0, stream>>>(cnt, N_TOT);
    count_idx<<<gE1, 256, 0, stream>>>(row1, cnt, E1);
    finish_deg<<<gN, 256, 0, stream>>>(cnt, deg1, dinv1, N_TOT);
    zero_i32<<<gN, 256, 0, stream>>>(cnt, N_TOT);
    count_idx<<<gE1, 256, 0, stream>>>(col1, cnt, E1);
    scan_block<<<NB_SCAN, 256, 0, stream>>>(cnt, off1, bsum, N_TOT);
    scan_small<<<1, 512, 0, stream>>>(bsum, NB_SCAN, off1 + N_TOT);
    add_boff<<<gN, 256, 0, stream>>>(off1, bsum, N_TOT);
    zero_i32<<<gN, 256, 0, stream>>>(cnt, N_TOT);
    fill_csr<<<gE1, 256, 0, stream>>>(row1, col1, cnt, off1, src1, E1);
    // set 2
    zero_i32<<<gN, 256, 0, stream>>>(cnt, N_TOT);
    count_idx<<<gE2, 256, 0, stream>>>(row2, cnt, E2);
    finish_deg<<<gN, 256, 0, stream>>>(cnt, deg2, dinv2, N_TOT);
    zero_i32<<<gN, 256, 0, stream>>>(cnt, N_TOT);
    count_idx<<<gE2, 256, 0, stream>>>(col2, cnt, E2);
    scan_block<<<NB_SCAN, 256, 0, stream>>>(cnt, off2, bsum, N_TOT);
    scan_small<<<1, 512, 0, stream>>>(bsum, NB_SCAN, off2 + N_TOT);
    add_boff<<<gN, 256, 0, stream>>>(off2, bsum, N_TOT);
    zero_i32<<<gN, 256, 0, stream>>>(cnt, N_TOT);
    fill_csr<<<gE2, 256, 0, stream>>>(row2, col2, cnt, off2, src2, E2);

    // ---- 3 layers x (conv, re_conv) ----
    const float* hcur = h0;
    for (int l = 0; l < 3; ++l) {
        gemm_bias_act<<<dim3(2, (N_TOT + 63) / 64), 256, 0, stream>>>(
            hcur, conv_W + (size_t)l * EMB * EMB, conv_b + l * EMB, A, N_TOT, EMB, EMB, 0);
        gather_conv<<<(N_TOT + 3) / 4, 256, 0, stream>>>(
            A, off1, src1, dinv1, deg1, conv_root + l * EMB, B);

        gemm_bias_act<<<dim3(2, (N_TOT + 63) / 64), 256, 0, stream>>>(
            B, reconv_W + (size_t)l * EMB * EMB, reconv_b + l * EMB, A, N_TOT, EMB, EMB, 0);
        gather_conv<<<(N_TOT + 3) / 4, 256, 0, stream>>>(
            A, off2, src2, dinv2, deg2, reconv_root + l * EMB, B);

        ln_final<<<(N_TOT + 3) / 4, 256, 0, stream>>>(B, h0, ln_g + l * EMB, ln_b + l * EMB, out, l + 1);
        hcur = B;
    }
}

// Round 3
// 3136.447 us; speedup vs baseline: 4.0578x; 1.5854x over previous
//
#include <hip/hip_runtime.h>
#include <hip/hip_bf16.h>

// GNN_node bipartite GCN, Round 3: bf16 feature pipeline + MFMA GEMM.
// ws: Ab | Bb | h0b | xb | xnb | Wb | deg/dinv x2 | off1 src1 off2 src2 | cntA cntB bsum

#define N_INST 300000
#define N_NET  100000
#define N_TOT  400000
#define EMB    128
#define NB_SCAN ((N_TOT + 1023) / 1024)
#define LEAKY(v) ((v) > 0.f ? (v) : 0.1f * (v))

typedef __hip_bfloat16 bf16;
typedef __attribute__((ext_vector_type(8))) short short8;
typedef __attribute__((ext_vector_type(4))) float f32x4;

static constexpr size_t NF = (size_t)N_TOT * EMB;

__device__ __forceinline__ void gload16(const void* g, void* l) {
    __builtin_amdgcn_global_load_lds(
        (const __attribute__((address_space(1))) void*)g,
        (__attribute__((address_space(3))) void*)l, 16, 0, 0);
}

// ---------------- bf16 MFMA GEMM: C[M,N] = act(A[M,K] @ W[N,K]^T + b), C in bf16 ----
// 128x128 tile, 4 waves (2x2), each wave 64x64 via 4x4 16x16x32 frags.
__global__ __launch_bounds__(256) void gemm_mfma(
    const bf16* __restrict__ A, const bf16* __restrict__ W,
    const float* __restrict__ bias, bf16* __restrict__ C,
    int M, int N, int K, int act)
{
    __shared__ bf16 As[128 * 32];
    __shared__ bf16 Bs[128 * 32];
    const int t    = threadIdx.x;
    const int lane = t & 63, wid = t >> 6;
    const int wrow = (wid >> 1) << 6, wcol = (wid & 1) << 6;
    const int m0 = blockIdx.y << 7, n0 = blockIdx.x << 7;
    const int r = lane & 15, g = lane >> 4;

    f32x4 acc[4][4] = {};

    for (int k0 = 0; k0 < K; k0 += 32) {
        #pragma unroll
        for (int is = 0; is < 2; ++is) {
            int chunk = (is << 8) + t;          // 0..511 ; 16B per chunk
            int row = chunk >> 2;
            int kc  = (chunk & 3) << 3;         // k offset in elems
            int ga = m0 + row; if (ga > M - 1) ga = M - 1;
            gload16(A + (size_t)ga * K + k0 + kc, As + (size_t)((is << 8) + (wid << 6)) * 8);
            int gb = n0 + row; if (gb > N - 1) gb = N - 1;
            gload16(W + (size_t)gb * K + k0 + kc, Bs + (size_t)((is << 8) + (wid << 6)) * 8);
        }
        __syncthreads();
        short8 af[4], bg[4];
        #pragma unroll
        for (int f = 0; f < 4; ++f) {
            af[f] = *(const short8*)&As[(wrow + (f << 4) + r) * 32 + (g << 3)];
            bg[f] = *(const short8*)&Bs[(wcol + (f << 4) + r) * 32 + (g << 3)];
        }
        #pragma unroll
        for (int fi = 0; fi < 4; ++fi)
            #pragma unroll
            for (int fj = 0; fj < 4; ++fj)
                acc[fi][fj] = __builtin_amdgcn_mfma_f32_16x16x32_bf16(
                    af[fi], bg[fj], acc[fi][fj], 0, 0, 0);
        __syncthreads();
    }

    const int r4 = g << 2;
    #pragma unroll
    for (int fi = 0; fi < 4; ++fi) {
        #pragma unroll
        for (int fj = 0; fj < 4; ++fj) {
            int col = n0 + wcol + (fj << 4) + r;
            float bv = bias[col];
            #pragma unroll
            for (int q = 0; q < 4; ++q) {
                int m = m0 + wrow + (fi << 4) + r4 + q;
                if (m < M) {
                    float v = acc[fi][fj][q] + bv;
                    if (act) v = LEAKY(v);
                    C[(size_t)m * N + col] = __float2bfloat16(v);
                }
            }
        }
    }
}

// ---------------- converts ----------------
__global__ __launch_bounds__(256) void cvt_f32_bf16(const float* __restrict__ s,
                                                    bf16* __restrict__ d, int n) {
    int i = (blockIdx.x * 256 + threadIdx.x) << 2;
    if (i >= n) return;
    float4 v = *(const float4*)&s[i];
    __hip_bfloat162 p0, p1;
    p0.x = __float2bfloat16(v.x); p0.y = __float2bfloat16(v.y);
    p1.x = __float2bfloat16(v.z); p1.y = __float2bfloat16(v.w);
    *(__hip_bfloat162*)&d[i]     = p0;
    *(__hip_bfloat162*)&d[i + 2] = p1;
}

// ---------------- CSR / degree ----------------
__global__ __launch_bounds__(256) void zero_i32(int* __restrict__ p, int n) {
    int i = blockIdx.x * 256 + threadIdx.x;
    if (i < n) p[i] = 0;
}

__global__ __launch_bounds__(256) void count_both(const int* __restrict__ row,
                                                  const int* __restrict__ col,
                                                  int* __restrict__ cntr,
                                                  int* __restrict__ cntc, int E) {
    int e = blockIdx.x * 256 + threadIdx.x;
    if (e < E) {
        atomicAdd(&cntr[row[e]], 1);
        atomicAdd(&cntc[col[e]], 1);
    }
}

__global__ __launch_bounds__(256) void finish_deg(const int* __restrict__ rowcnt,
                                                  float* __restrict__ deg,
                                                  float* __restrict__ dinv, int n) {
    int i = blockIdx.x * 256 + threadIdx.x;
    if (i < n) {
        float d = (float)rowcnt[i] + 1.0f;
        deg[i]  = d;
        dinv[i] = rsqrtf(d);
    }
}

__global__ __launch_bounds__(256) void scan_block(const int* __restrict__ cnt,
                                                  int* __restrict__ off,
                                                  int* __restrict__ bsum, int n) {
    __shared__ int sh[256];
    int t = threadIdx.x;
    int base = blockIdx.x * 1024 + t * 4;
    int v0 = base + 0 < n ? cnt[base + 0] : 0;
    int v1 = base + 1 < n ? cnt[base + 1] : 0;
    int v2 = base + 2 < n ? cnt[base + 2] : 0;
    int v3 = base + 3 < n ? cnt[base + 3] : 0;
    int s01 = v0 + v1, loc = s01 + v2 + v3;
    sh[t] = loc;
    __syncthreads();
    #pragma unroll
    for (int o = 1; o < 256; o <<= 1) {
        int x_ = (t >= o) ? sh[t - o] : 0;
        __syncthreads();
        sh[t] += x_;
        __syncthreads();
    }
    int excl = sh[t] - loc;
    if (t == 255) bsum[blockIdx.x] = sh[255];
    if (base + 0 < n) off[base + 0] = excl;
    if (base + 1 < n) off[base + 1] = excl + v0;
    if (base + 2 < n) off[base + 2] = excl + s01;
    if (base + 3 < n) off[base + 3] = excl + s01 + v2;
}

__global__ __launch_bounds__(512) void scan_small(int* __restrict__ bsum, int nb,
                                                  int* __restrict__ off_end) {
    __shared__ int sh[512];
    int t = threadIdx.x;
    int v = t < nb ? bsum[t] : 0;
    sh[t] = v;
    __syncthreads();
    #pragma unroll
    for (int o = 1; o < 512; o <<= 1) {
        int x_ = (t >= o) ? sh[t - o] : 0;
        __syncthreads();
        sh[t] += x_;
        __syncthreads();
    }
    if (t < nb) bsum[t] = sh[t] - v;
    if (t == 511) *off_end = sh[511];
}

__global__ __launch_bounds__(256) void add_boff(int* __restrict__ off,
                                                const int* __restrict__ bsum, int n) {
    int i = blockIdx.x * 256 + threadIdx.x;
    if (i < n) off[i] += bsum[i >> 10];
}

__global__ __launch_bounds__(256) void fill_csr(const int* __restrict__ row,
                                                const int* __restrict__ col,
                                                int* __restrict__ cursor,
                                                const int* __restrict__ off,
                                                int* __restrict__ src, int E) {
    int e = blockIdx.x * 256 + threadIdx.x;
    if (e >= E) return;
    int c = col[e];
    int p = off[c] + atomicAdd(&cursor[c], 1);
    src[p] = row[e];
}

// ---------------- fused conv aggregate (CSR gather + self/root), bf16 ----------------
__global__ __launch_bounds__(256) void gather_conv(const bf16* __restrict__ x,
                                                   const int* __restrict__ off,
                                                   const int* __restrict__ src,
                                                   const float* __restrict__ dinv,
                                                   const float* __restrict__ deg,
                                                   const float* __restrict__ root,
                                                   bf16* __restrict__ outb) {
    int i = blockIdx.x * 4 + (threadIdx.x >> 6);
    if (i >= N_TOT) return;
    int lane = threadIdx.x & 63;
    int f = lane << 1;
    __hip_bfloat162 xv = *(const __hip_bfloat162*)&x[(size_t)i * EMB + f];
    float invd = 1.0f / deg[i];
    float a0 = fmaxf(__bfloat162float(xv.x) + root[f], 0.f) * invd;
    float a1 = fmaxf(__bfloat162float(xv.y) + root[f + 1], 0.f) * invd;
    float di = dinv[i];
    int e0 = off[i], e1 = off[i + 1];
    for (int e = e0; e < e1; ++e) {
        int s = src[e];
        float w = dinv[s] * di;
        __hip_bfloat162 v = *(const __hip_bfloat162*)&x[(size_t)s * EMB + f];
        a0 = fmaf(fmaxf(__bfloat162float(v.x), 0.f), w, a0);
        a1 = fmaf(fmaxf(__bfloat162float(v.y), 0.f), w, a1);
    }
    __hip_bfloat162 o;
    o.x = __float2bfloat16(a0); o.y = __float2bfloat16(a1);
    *(__hip_bfloat162*)&outb[(size_t)i * EMB + f] = o;
}

// ---------------- LN + residual + leaky; h updated bf16, net rows -> out fp32 -------
__global__ __launch_bounds__(256) void ln_final(bf16* __restrict__ h,
                                                const bf16* __restrict__ h0,
                                                const float* __restrict__ gw,
                                                const float* __restrict__ bw,
                                                float* __restrict__ out, int slice) {
    int i = blockIdx.x * 4 + (threadIdx.x >> 6);
    if (i >= N_TOT) return;
    int lane = threadIdx.x & 63;
    size_t base = (size_t)i * EMB + (lane << 1);
    __hip_bfloat162 t2 = *(const __hip_bfloat162*)&h[base];
    __hip_bfloat162 z2 = *(const __hip_bfloat162*)&h0[base];
    float t0 = __bfloat162float(t2.x) + __bfloat162float(z2.x);
    float t1 = __bfloat162float(t2.y) + __bfloat162float(z2.y);
    float s = t0 + t1, sq = t0 * t0 + t1 * t1;
    #pragma unroll
    for (int o = 1; o < 64; o <<= 1) {
        s  += __shfl_xor(s, o);
        sq += __shfl_xor(sq, o);
    }
    float m   = s * (1.f / 128.f);
    float var = sq * (1.f / 128.f) - m * m;
    float rs  = rsqrtf(var + 1e-5f);
    int f = lane << 1;
    float y0 = (t0 - m) * rs * gw[f]     + bw[f];
    float y1 = (t1 - m) * rs * gw[f + 1] + bw[f + 1];
    y0 = LEAKY(y0); y1 = LEAKY(y1);
    __hip_bfloat162 o2;
    o2.x = __float2bfloat16(y0); o2.y = __float2bfloat16(y1);
    *(__hip_bfloat162*)&h[base] = o2;
    if (i >= N_INST) {
        size_t ob = (size_t)(i - N_INST) * 512 + (size_t)slice * EMB + f;
        *(float2*)&out[ob] = make_float2(y0, y1);
    }
}

__global__ __launch_bounds__(256) void copy_h0_out(const bf16* __restrict__ h0,
                                                   float* __restrict__ out) {
    int idx = blockIdx.x * 256 + threadIdx.x;
    if (idx >= N_NET * 32) return;
    int n = idx >> 5, g4 = (idx & 31) << 2;
    const __hip_bfloat162* p = (const __hip_bfloat162*)&h0[(size_t)(N_INST + n) * EMB + g4];
    __hip_bfloat162 a = p[0], b = p[1];
    float4 o = make_float4(__bfloat162float(a.x), __bfloat162float(a.y),
                           __bfloat162float(b.x), __bfloat162float(b.y));
    *(float4*)&out[(size_t)n * 512 + g4] = o;
}

// ---------------- host ----------------
extern "C" void kernel_launch(void* const* d_in, const int* in_sizes, int n_in,
                              void* d_out, int out_size, void* d_ws, size_t ws_size,
                              hipStream_t stream)
{
    const float* x        = (const float*)d_in[0];
    const float* x_net    = (const float*)d_in[1];
    const int*   ei1      = (const int*)d_in[2];
    const int*   ei2      = (const int*)d_in[3];
    const float* enc1_W   = (const float*)d_in[5];
    const float* enc1_b   = (const float*)d_in[6];
    const float* enc2_W   = (const float*)d_in[7];
    const float* enc2_b   = (const float*)d_in[8];
    const float* encn1_W  = (const float*)d_in[9];
    const float* encn1_b  = (const float*)d_in[10];
    const float* encn2_W  = (const float*)d_in[11];
    const float* encn2_b  = (const float*)d_in[12];
    const float* conv_W   = (const float*)d_in[13];
    const float* conv_b   = (const float*)d_in[14];
    const float* conv_root= (const float*)d_in[15];
    const float* reconv_W = (const float*)d_in[16];
    const float* reconv_b = (const float*)d_in[17];
    const float* reconv_root = (const float*)d_in[18];
    const float* ln_g     = (const float*)d_in[19];
    const float* ln_b     = (const float*)d_in[20];
    float* out = (float*)d_out;

    const int E1 = in_sizes[2] / 2;
    const int E2 = in_sizes[3] / 2;
    const int* row1 = ei1;       const int* col1 = ei1 + E1;
    const int* row2 = ei2;       const int* col2 = ei2 + E2;

    bf16* Ab  = (bf16*)d_ws;
    bf16* Bb  = Ab + NF;
    bf16* h0b = Bb + NF;
    bf16* xb  = h0b + NF;                        // [N_INST][64]
    bf16* xnb = xb + (size_t)N_INST * 64;        // [N_NET][64]
    bf16* Wb  = xnb + (size_t)N_NET * 64;        // all weights bf16
    const int WENC1 = 0, WENC2 = 16384, WENCN1 = 49152, WENCN2 = 57344,
              WCONV = 73728, WRECONV = 122880, WTOT = 172032;
    float* deg1  = (float*)(Wb + WTOT);
    float* dinv1 = deg1 + N_TOT;
    float* deg2  = dinv1 + N_TOT;
    float* dinv2 = deg2 + N_TOT;
    int* off1 = (int*)(dinv2 + N_TOT);
    int* src1 = off1 + N_TOT + 1;
    int* off2 = src1 + E1;
    int* src2 = off2 + N_TOT + 1;
    int* cntA = src2 + E2;
    int* cntB = cntA + N_TOT;
    int* bsum = cntB + N_TOT;

    bf16* hid  = Ab;   // [N_INST][256] spans Ab + part of Bb (scratch in encoder phase)
    bf16* hidn = Ab;   // [N_NET][128]  (after hid consumed)

    // ---- fp32 -> bf16 converts ----
    cvt_f32_bf16<<<(N_INST * 64 / 4 + 255) / 256, 256, 0, stream>>>(x, xb, N_INST * 64);
    cvt_f32_bf16<<<(N_NET * 64 / 4 + 255) / 256, 256, 0, stream>>>(x_net, xnb, N_NET * 64);
    cvt_f32_bf16<<<16, 256, 0, stream>>>(enc1_W,  Wb + WENC1,  16384);
    cvt_f32_bf16<<<32, 256, 0, stream>>>(enc2_W,  Wb + WENC2,  32768);
    cvt_f32_bf16<<< 8, 256, 0, stream>>>(encn1_W, Wb + WENCN1,  8192);
    cvt_f32_bf16<<<16, 256, 0, stream>>>(encn2_W, Wb + WENCN2, 16384);
    cvt_f32_bf16<<<48, 256, 0, stream>>>(conv_W,  Wb + WCONV,  49152);
    cvt_f32_bf16<<<48, 256, 0, stream>>>(reconv_W,Wb + WRECONV,49152);

    // ---- encoders (MFMA) ----
    gemm_mfma<<<dim3(2, (N_INST + 127) / 128), 256, 0, stream>>>(
        xb, Wb + WENC1, enc1_b, hid, N_INST, 256, 64, 1);
    gemm_mfma<<<dim3(1, (N_INST + 127) / 128), 256, 0, stream>>>(
        hid, Wb + WENC2, enc2_b, h0b, N_INST, 128, 256, 1);
    gemm_mfma<<<dim3(1, (N_NET + 127) / 128), 256, 0, stream>>>(
        xnb, Wb + WENCN1, encn1_b, hidn, N_NET, 128, 64, 1);
    gemm_mfma<<<dim3(1, (N_NET + 127) / 128), 256, 0, stream>>>(
        hidn, Wb + WENCN2, encn2_b, h0b + (size_t)N_INST * EMB, N_NET, 128, 128, 1);
    copy_h0_out<<<(N_NET * 32 + 255) / 256, 256, 0, stream>>>(h0b, out);

    const int gE1 = (E1 + 255) / 256, gE2 = (E2 + 255) / 256;
    const int gN  = (N_TOT + 255) / 256, gN2 = (2 * N_TOT + 255) / 256;

    // ---- CSR build, set 1 ----
    zero_i32<<<gN2, 256, 0, stream>>>(cntA, 2 * N_TOT);
    count_both<<<gE1, 256, 0, stream>>>(row1, col1, cntA, cntB, E1);
    finish_deg<<<gN, 256, 0, stream>>>(cntA, deg1, dinv1, N_TOT);
    scan_block<<<NB_SCAN, 256, 0, stream>>>(cntB, off1, bsum, N_TOT);
    scan_small<<<1, 512, 0, stream>>>(bsum, NB_SCAN, off1 + N_TOT);
    add_boff<<<gN, 256, 0, stream>>>(off1, bsum, N_TOT);
    zero_i32<<<gN, 256, 0, stream>>>(cntA, N_TOT);
    fill_csr<<<gE1, 256, 0, stream>>>(row1, col1, cntA, off1, src1, E1);
    // ---- CSR build, set 2 ----
    zero_i32<<<gN2, 256, 0, stream>>>(cntA, 2 * N_TOT);
    count_both<<<gE2, 256, 0, stream>>>(row2, col2, cntA, cntB, E2);
    finish_deg<<<gN, 256, 0, stream>>>(cntA, deg2, dinv2, N_TOT);
    scan_block<<<NB_SCAN, 256, 0, stream>>>(cntB, off2, bsum, N_TOT);
    scan_small<<<1, 512, 0, stream>>>(bsum, NB_SCAN, off2 + N_TOT);
    add_boff<<<gN, 256, 0, stream>>>(off2, bsum, N_TOT);
    zero_i32<<<gN, 256, 0, stream>>>(cntA, N_TOT);
    fill_csr<<<gE2, 256, 0, stream>>>(row2, col2, cntA, off2, src2, E2);

    // ---- 3 layers x (conv, re_conv) ----
    const bf16* hcur = h0b;
    for (int l = 0; l < 3; ++l) {
        gemm_mfma<<<dim3(1, (N_TOT + 127) / 128), 256, 0, stream>>>(
            hcur, Wb + WCONV + l * 16384, conv_b + l * EMB, Ab, N_TOT, EMB, EMB, 0);
        gather_conv<<<(N_TOT + 3) / 4, 256, 0, stream>>>(
            Ab, off1, src1, dinv1, deg1, conv_root + l * EMB, Bb);

        gemm_mfma<<<dim3(1, (N_TOT + 127) / 128), 256, 0, stream>>>(
            Bb, Wb + WRECONV + l * 16384, reconv_b + l * EMB, Ab, N_TOT, EMB, EMB, 0);
        gather_conv<<<(N_TOT + 3) / 4, 256, 0, stream>>>(
            Ab, off2, src2, dinv2, deg2, reconv_root + l * EMB, Bb);

        ln_final<<<(N_TOT + 3) / 4, 256, 0, stream>>>(
            Bb, h0b, ln_g + l * EMB, ln_b + l * EMB, out, l + 1);
        hcur = Bb;
    }
}